// Round 9
// baseline (417.927 us; speedup 1.0000x reference)
//
#include <hip/hip_runtime.h>
#include <stdint.h>

#define IC    4096
#define BLK   512          // 8 waves per block
#define VPT   2            // float4 chunks per thread per row
#define EPT   8            // elements per thread (512*8 = 4096 = one row)
#define RPB   4            // rows per block, software-pipelined

// ---- 8-wave block reductions; disjoint LDS regions -> no trailing barrier.
// Region reuse across rows is separated by >=2 barriers (safe).
__device__ __forceinline__ void bred_df(double& a, float& p, double* smd, float* smf) {
    #pragma unroll
    for (int off = 32; off; off >>= 1) { a += __shfl_xor(a, off); p += __shfl_xor(p, off); }
    const int wid = threadIdx.x >> 6;
    if ((threadIdx.x & 63) == 0) { smd[wid] = a; smf[wid] = p; }
    __syncthreads();
    a = ((smd[0]+smd[1])+(smd[2]+smd[3])) + ((smd[4]+smd[5])+(smd[6]+smd[7]));
    p = ((smf[0]+smf[1])+(smf[2]+smf[3])) + ((smf[4]+smf[5])+(smf[6]+smf[7]));
}

__device__ __forceinline__ double bred_d(double a, double* smd) {
    #pragma unroll
    for (int off = 32; off; off >>= 1) a += __shfl_xor(a, off);
    const int wid = threadIdx.x >> 6;
    if ((threadIdx.x & 63) == 0) smd[wid] = a;
    __syncthreads();
    return ((smd[0]+smd[1])+(smd[2]+smd[3])) + ((smd[4]+smd[5])+(smd[6]+smd[7]));
}

__device__ __forceinline__ uint32_t byte4_to_bits(uint32_t w) {
    return (uint32_t)((w & 0x000000ffu) != 0)
         | ((uint32_t)((w & 0x0000ff00u) != 0) << 1)
         | ((uint32_t)((w & 0x00ff0000u) != 0) << 2)
         | ((uint32_t)((w & 0xff000000u) != 0) << 3);
}

// ---- one row: passes A,B,D + epilogue (verified R4-lineage numerics) ----
__device__ __forceinline__ void row_compute(
    const float (&xin)[EPT], uint32_t mb, float4* orow4,
    int tid, double* smd, float* smf)
{
    float xm[EPT];     // x*m (exact)
    float sgm[EPT];    // pass B: sign1*m; pass D onward: (float)t2

    #pragma unroll
    for (int j = 0; j < EPT; ++j) xm[j] = ((mb >> j) & 1u) ? xin[j] : 0.f;

    // pass A: s = sum(x*m) [f64 dual accum], c = popc (exact)
    double s0 = 0.0, s1 = 0.0;
    #pragma unroll
    for (int j = 0; j < EPT; j += 2) { s0 += (double)xm[j]; s1 += (double)xm[j+1]; }
    double s  = s0 + s1;
    float  cf = (float)__popc(mb);
    bred_df(s, cf, smd + 0, smf + 0);                 // barrier 1

    const bool   has    = (cf > 0.f);
    const double c      = (double)cf;
    const double nmiss  = (double)(4096.f - cf);
    const double inv    = 1.0 / fmax(c, 1.0);
    const double mean1  = has ? s * inv : 0.0;
    const float  mean1f = (float)mean1;

    // pass B (f32 element math, f64 accumulate): sum|x*m - mean1f| over ALL
    // lanes (unmasked contribute exactly |mean1f| -> corrected after);
    // sign from f32 sub (Sterbenz-exact near boundary); d = sum sign1*m.
    double sa0 = 0.0, sa1 = 0.0;
    float  d0 = 0.f, d1 = 0.f;
    #pragma unroll
    for (int j = 0; j < EPT; ++j) {
        const float t  = xm[j] - mean1f;
        const float sg = (t > 0.f) ? 1.f : ((t < 0.f) ? -1.f : 0.f);
        const float sv = ((mb >> j) & 1u) ? sg : 0.f;
        sgm[j] = sv;
        if (j & 1) { d1 += sv; sa1 += (double)fabsf(t); }
        else       { d0 += sv; sa0 += (double)fabsf(t); }
    }
    double sa = sa0 + sa1;
    float  df = d0 + d1;
    bred_df(sa, df, smd + 8, smf + 8);                // barrier 2
    sa -= nmiss * (double)fabsf(mean1f);

    const double scale1 = has ? sa * inv : 0.0;
    // pass C eliminated: sum((x-b1)*m) = s - scale1*d - mean1*c
    const double mean2  = has ? (s - scale1 * (double)df - mean1 * c) * inv : 0.0;
    const double mean12 = mean1 + mean2;

    // pass D (f64): scale2 = mean |x - b1 - mean2| over mask.
    // Unmasked: sgm==0 -> t2 == -mean12 exactly -> corrected after.
    double sb0 = 0.0, sb1 = 0.0;
    #pragma unroll
    for (int j = 0; j < EPT; ++j) {
        const double t2 = (double)xm[j] - fma((double)sgm[j], scale1, mean12);
        sgm[j] = (float)t2;                           // reuse registers
        if (j & 1) sb1 += fabs(t2); else sb0 += fabs(t2);
    }
    double sa2 = bred_d(sb0 + sb1, smd + 16);         // barrier 3
    sa2 -= nmiss * fabs(mean12);
    const double scale2  = has ? sa2 * inv : 0.0;
    const float  scale2f = (float)scale2;

    // epilogue (f32): out = (b1 + sign2*scale2 + mean2)*m; b1+mean2 == x - t2;
    // sign2 from (float)t2 (sign-exact).
    #pragma unroll
    for (int i = 0; i < VPT; ++i) {
        float r[4];
        #pragma unroll
        for (int k = 0; k < 4; ++k) {
            const int j = 4 * i + k;
            const float t2f = sgm[j];
            const float b1f = xm[j] - t2f;
            const float sg2 = (t2f > 0.f) ? 1.f : ((t2f < 0.f) ? -1.f : 0.f);
            r[k] = ((mb >> j) & 1u) ? fmaf(sg2, scale2f, b1f) : 0.f;
        }
        float4 o; o.x = r[0]; o.y = r[1]; o.z = r[2]; o.w = r[3];
        orow4[tid + i * BLK] = o;
    }
}

__global__ __launch_bounds__(BLK, 8) void binarize_kernel(
    const float* __restrict__ x,
    const uint8_t* __restrict__ mask,
    float* __restrict__ out,
    int nrows)
{
    __shared__ double smd[24];   // 3 regions x 8 waves
    __shared__ float  smf[16];   // 2 regions x 8 waves
    const int tid  = threadIdx.x;
    const int lane = tid & 63;
    const int S    = gridDim.x;  // row stride between a block's rows

    // mask dtype detection (wave-uniform, grid-uniform result, no barrier):
    // int32 0/1 mask: every 32-bit word <= 1; byte mask: P(all 64 <= 1) ~ 0.
    const bool mask_is_i32 = !__any(((const uint32_t*)mask)[lane] > 1u);

    if (!mask_is_i32) {
        // ---- byte-mask path (the real input): software-pipelined rows.
        // Prefetch row k+1 raw (8+2 regs) before row k's compute, so next-row
        // HBM latency hides under this row's 3 reductions + epilogue.
        float4   nxa, nxb;
        uint32_t nma, nmb;
        {
            const int r = blockIdx.x;
            const float4*   xr = (const float4*)(x + (size_t)r * IC);
            const uint32_t* mr = (const uint32_t*)(mask + (size_t)r * IC);
            nxa = xr[tid];       nxb = xr[tid + BLK];
            nma = mr[tid];       nmb = mr[tid + BLK];
        }
        #pragma unroll
        for (int k = 0; k < RPB; ++k) {
            const int r = blockIdx.x + k * S;
            if (r >= nrows) break;                      // uniform per block
            float xin[EPT];
            xin[0] = nxa.x; xin[1] = nxa.y; xin[2] = nxa.z; xin[3] = nxa.w;
            xin[4] = nxb.x; xin[5] = nxb.y; xin[6] = nxb.z; xin[7] = nxb.w;
            const uint32_t mb = byte4_to_bits(nma) | (byte4_to_bits(nmb) << 4);

            const int rn = blockIdx.x + (k + 1) * S;    // issue next prefetch
            if (k + 1 < RPB && rn < nrows) {
                const float4*   xr = (const float4*)(x + (size_t)rn * IC);
                const uint32_t* mr = (const uint32_t*)(mask + (size_t)rn * IC);
                nxa = xr[tid];   nxb = xr[tid + BLK];
                nma = mr[tid];   nmb = mr[tid + BLK];
            }
            row_compute(xin, mb, (float4*)(out + (size_t)r * IC), tid, smd, smf);
        }
    } else {
        // ---- int32-mask path (correctness fallback, unpipelined) ----
        for (int k = 0; k < RPB; ++k) {
            const int r = blockIdx.x + k * S;
            if (r >= nrows) break;
            const float4* xr = (const float4*)(x + (size_t)r * IC);
            const int4*   mr = (const int4*)mask + (size_t)r * (IC / 4);
            float xin[EPT]; uint32_t mb = 0;
            #pragma unroll
            for (int i = 0; i < VPT; ++i) {
                const float4 v  = xr[tid + i * BLK];
                const int4   m4 = mr[tid + i * BLK];
                xin[4*i+0] = v.x; xin[4*i+1] = v.y; xin[4*i+2] = v.z; xin[4*i+3] = v.w;
                mb |= ((uint32_t)(m4.x != 0) | ((uint32_t)(m4.y != 0) << 1)
                    |  ((uint32_t)(m4.z != 0) << 2) | ((uint32_t)(m4.w != 0) << 3)) << (4 * i);
            }
            row_compute(xin, mb, (float4*)(out + (size_t)r * IC), tid, smd, smf);
        }
    }
}

extern "C" void kernel_launch(void* const* d_in, const int* in_sizes, int n_in,
                              void* d_out, int out_size, void* d_ws, size_t ws_size,
                              hipStream_t stream) {
    const float*   x    = (const float*)d_in[0];
    const uint8_t* mask = (const uint8_t*)d_in[1];
    float*         out  = (float*)d_out;

    const int rows = in_sizes[0] / IC;            // 11008
    const int grid = (rows + RPB - 1) / RPB;      // 2752; block b -> rows b, b+S, b+2S, b+3S
    binarize_kernel<<<grid, BLK, 0, stream>>>(x, mask, out, rows);
}